// Round 3
// baseline (1163.754 us; speedup 1.0000x reference)
//
#include <hip/hip_runtime.h>
#include <math.h>

#define BB 4
#define UU 512
#define DD 80
#define HH 8
#define FFND 2048
#define LL 12
#define SEGC 32
#define LCC 50
#define RCC 8
#define NSEG 16
#define RCL 128
#define KK 640
#define ROWS (BB*KK)        // 2560
#define OUTD 768
#define EPSF 1e-5f
#define SCALEF 0.31622776601683794f  // (D/H)^-0.5

typedef __attribute__((ext_vector_type(8))) short bf16x8;
typedef __attribute__((ext_vector_type(4))) float f32x4;

__device__ inline unsigned short f2bf(float f) {
  unsigned int u = __float_as_uint(f);
  u += 0x7fffu + ((u >> 16) & 1u);
  return (unsigned short)(u >> 16);
}
__device__ inline ushort4 f4bf(float4 v) {
  ushort4 r;
  r.x = f2bf(v.x); r.y = f2bf(v.y); r.z = f2bf(v.z); r.w = f2bf(v.w);
  return r;
}

// ---------------- gather: x0 = concat(rc, utt) ----------------
__global__ __launch_bounds__(256) void k_gather(const float* __restrict__ mel,
                                                float* __restrict__ x) {
  int idx = blockIdx.x * 256 + threadIdx.x;
  if (idx >= ROWS * DD) return;
  int d = idx % DD;
  int row = idx / DD;
  int b = row / KK;
  int j = row % KK;
  int pos;
  if (j < RCL) {
    int i = j >> 3, r = j & 7;
    pos = (i < NSEG - 1) ? (i + 1) * SEGC + r : UU + r;
  } else {
    pos = j - RCL;
  }
  x[idx] = mel[(b * (UU + RCC) + pos) * DD + d];
}

// ---------------- convert ALL weights fp32 -> bf16 ----------------
// ranges (in float4 units): W1 491520 | W2 491520 | Wq 19200 | Wkv 38400 | Wo 19200 | Wp 15360
__global__ __launch_bounds__(256) void k_cvt(
    const float* __restrict__ W1, const float* __restrict__ W2,
    const float* __restrict__ Wq, const float* __restrict__ Wkv,
    const float* __restrict__ Wo, const float* __restrict__ Wp,
    unsigned short* __restrict__ o1, unsigned short* __restrict__ o2,
    unsigned short* __restrict__ oq, unsigned short* __restrict__ okv,
    unsigned short* __restrict__ oo, unsigned short* __restrict__ op) {
  int t = blockIdx.x * 256 + threadIdx.x;
  const float* src; unsigned short* dst; int i;
  if (t < 491520)       { src = W1;  dst = o1;  i = t; }
  else if (t < 983040)  { src = W2;  dst = o2;  i = t - 491520; }
  else if (t < 1002240) { src = Wq;  dst = oq;  i = t - 983040; }
  else if (t < 1040640) { src = Wkv; dst = okv; i = t - 1002240; }
  else if (t < 1059840) { src = Wo;  dst = oo;  i = t - 1040640; }
  else                  { src = Wp;  dst = op;  i = t - 1059840; }
  float4 v = reinterpret_cast<const float4*>(src)[i];
  reinterpret_cast<ushort4*>(dst)[i] = f4bf(v);
}

// ---------------- A: LN_in fused + QKV GEMM (bf16 MFMA) ----------------
// grid (ROWS/64, 3), block 256 (4 waves). ct: 0->q, 1->k, 2->v (80 cols each)
__global__ __launch_bounds__(256) void k_qkvm(
    const float* __restrict__ x, float* __restrict__ qkv,
    const unsigned short* __restrict__ wq, const float* __restrict__ bq,
    const unsigned short* __restrict__ wkv, const float* __restrict__ bkv,
    const float* __restrict__ lg, const float* __restrict__ lb) {
  __shared__ float s_xf[64 * 84];
  __shared__ unsigned short s_a[64 * 104];
  __shared__ unsigned short s_w[80 * 104];
  __shared__ float s_mu[64], s_ri[64];
  int tid = threadIdx.x;
  int r0 = blockIdx.x * 64;
  int ct = blockIdx.y;
  // load x tile (fp32)
  for (int k = 0; k < 5; ++k) {
    int idx = tid + k * 256;  // 1280 = 64 rows x 20 float4
    int row = idx / 20, c4 = idx % 20;
    *reinterpret_cast<float4*>(&s_xf[row * 84 + c4 * 4]) =
        *reinterpret_cast<const float4*>(&x[(r0 + row) * DD + c4 * 4]);
  }
  // load weight tile (bf16), 80 rows x 10 uint4
  const unsigned short* wbase = (ct == 0) ? wq : (ct == 1 ? wkv : (wkv + 80 * DD));
  for (int k = 0; k < 4; ++k) {
    int idx = tid + k * 256;
    if (idx < 800) {
      int row = idx / 10, ch = idx % 10;
      *reinterpret_cast<uint4*>(&s_w[row * 104 + ch * 8]) =
          *reinterpret_cast<const uint4*>(&wbase[row * DD + ch * 8]);
    }
  }
  // zero K-pad
  if (tid < 128) {
    int row = tid >> 1, half = tid & 1;
    *reinterpret_cast<uint4*>(&s_a[row * 104 + 80 + half * 8]) = make_uint4(0,0,0,0);
  }
  if (tid < 160) {
    int row = tid >> 1, half = tid & 1;
    *reinterpret_cast<uint4*>(&s_w[row * 104 + 80 + half * 8]) = make_uint4(0,0,0,0);
  }
  __syncthreads();
  // LN stats: 4 threads/row
  {
    int row = tid >> 2, t4 = tid & 3;
    float sm = 0.f, sq = 0.f;
    for (int d = t4 * 20; d < t4 * 20 + 20; ++d) {
      float v = s_xf[row * 84 + d];
      sm += v; sq += v * v;
    }
    sm += __shfl_xor(sm, 1, 4); sq += __shfl_xor(sq, 1, 4);
    sm += __shfl_xor(sm, 2, 4); sq += __shfl_xor(sq, 2, 4);
    if (t4 == 0) {
      float mu = sm * (1.f / DD);
      s_mu[row] = mu;
      s_ri[row] = rsqrtf(sq * (1.f / DD) - mu * mu + EPSF);
    }
  }
  __syncthreads();
  // normalize + cast to bf16
  {
    int row = tid >> 2, c0 = (tid & 3) * 20;
    float mu = s_mu[row], ri = s_ri[row];
    for (int j = 0; j < 5; ++j) {
      int c = c0 + j * 4;
      float4 v = *reinterpret_cast<const float4*>(&s_xf[row * 84 + c]);
      v.x = (v.x - mu) * ri * lg[c] + lb[c];
      v.y = (v.y - mu) * ri * lg[c + 1] + lb[c + 1];
      v.z = (v.z - mu) * ri * lg[c + 2] + lb[c + 2];
      v.w = (v.w - mu) * ri * lg[c + 3] + lb[c + 3];
      *reinterpret_cast<ushort4*>(&s_a[row * 104 + c]) = f4bf(v);
    }
  }
  __syncthreads();
  int w = tid >> 6, lane = tid & 63;
  int m = lane & 15, q = lane >> 4;
  f32x4 acc[5] = {};
#pragma unroll
  for (int kk = 0; kk < 3; ++kk) {
    bf16x8 a = *reinterpret_cast<const bf16x8*>(&s_a[(w * 16 + m) * 104 + kk * 32 + q * 8]);
#pragma unroll
    for (int c5 = 0; c5 < 5; ++c5) {
      bf16x8 b = *reinterpret_cast<const bf16x8*>(&s_w[(c5 * 16 + m) * 104 + kk * 32 + q * 8]);
      acc[c5] = __builtin_amdgcn_mfma_f32_16x16x32_bf16(a, b, acc[c5], 0, 0, 0);
    }
  }
  const float* bias = (ct == 0) ? bq : (bkv + (ct == 2 ? 80 : 0));
#pragma unroll
  for (int c5 = 0; c5 < 5; ++c5) {
    int c = c5 * 16 + m;
    float bv = bias[c];
#pragma unroll
    for (int r = 0; r < 4; ++r) {
      int grow = r0 + w * 16 + q * 4 + r;
      qkv[grow * 240 + ct * 80 + c] = acc[c5][r] + bv;
    }
  }
}

// ---------------- B: masked segmented attention (conflict-free) ----------------
// grid (NSEG, H, B), block 64
__global__ __launch_bounds__(64) void k_attn(const float* __restrict__ qkv,
                                             float* __restrict__ attn,
                                             const int* __restrict__ lengths) {
  int i = blockIdx.x, h = blockIdx.y, b = blockIdx.z;
  int tid = threadIdx.x;
  int s = i * SEGC - LCC; if (s < 0) s = 0;
  int e = (i + 1) * SEGC;
  int nk = RCC + (e - s);  // 40..90
  __shared__ float s_k[10 * 97], s_v[10 * 97], s_q[10 * 44];
  __shared__ float s_p[40 * 91], s_kb[90], s_den[40];
  int len = lengths[b];
  for (int j = tid; j < nk; j += 64) {
    int kr = (j < RCC) ? i * RCC + j : RCL + s + (j - RCC);
    const float* kp = &qkv[(b * KK + kr) * 240 + 80 + h * 10];
#pragma unroll
    for (int d = 0; d < 10; ++d) {
      s_k[d * 97 + j] = kp[d];
      s_v[d * 97 + j] = kp[80 + d];
    }
    s_kb[j] = (kr >= len + RCL) ? -1e8f : 0.f;
  }
  if (tid < 40) {
    int qr = (tid < RCC) ? i * RCC + tid : RCL + i * SEGC + (tid - RCC);
    const float* qp = &qkv[(b * KK + qr) * 240 + h * 10];
#pragma unroll
    for (int d = 0; d < 10; ++d) s_q[d * 44 + tid] = qp[d];
  }
  __syncthreads();
  for (int q = 0; q < 40; ++q) {
    for (int jk = tid; jk < nk; jk += 64) {
      float dot = 0.f;
#pragma unroll
      for (int d = 0; d < 10; ++d) dot += s_q[d * 44 + q] * s_k[d * 97 + jk];
      s_p[q * 91 + jk] = dot * SCALEF + s_kb[jk];
    }
  }
  __syncthreads();
  if (tid < 40) {
    float mx = -1e30f;
    for (int kx = 0; kx < nk; ++kx) mx = fmaxf(mx, s_p[tid * 91 + kx]);
    float sum = 0.f;
    for (int kx = 0; kx < nk; ++kx) {
      float ev = __expf(s_p[tid * 91 + kx] - mx);
      s_p[tid * 91 + kx] = ev;
      sum += ev;
    }
    s_den[tid] = 1.f / sum;
  }
  __syncthreads();
  int d = tid & 15, qoff = tid >> 4;
  if (d < 10) {
    for (int pass = 0; pass < 10; ++pass) {
      int q = pass * 4 + qoff;
      float o = 0.f;
      for (int kx = 0; kx < nk; ++kx) o += s_p[q * 91 + kx] * s_v[d * 97 + kx];
      int qr = (q < RCC) ? i * RCC + q : RCL + i * SEGC + (q - RCC);
      attn[(b * KK + qr) * DD + h * 10 + d] = o * s_den[q];
    }
  }
}

// ---------------- C: out-proj MFMA + bias + residual + LN_ff ----------------
// grid ROWS/64, block 256 (4 waves)
__global__ __launch_bounds__(256) void k_oprojm(
    const float* __restrict__ attn, const unsigned short* __restrict__ wo,
    const float* __restrict__ bo, const float* __restrict__ x,
    float* __restrict__ res, unsigned short* __restrict__ ffln_bf,
    const float* __restrict__ fg, const float* __restrict__ fb) {
  __shared__ unsigned short s_a[64 * 104];
  __shared__ unsigned short s_w[80 * 104];
  __shared__ float s_x2[64 * 84];
  int tid = threadIdx.x;
  int r0 = blockIdx.x * 64;
  for (int k = 0; k < 5; ++k) {
    int idx = tid + k * 256;  // 1280
    int row = idx / 20, c4 = idx % 20;
    float4 a = *reinterpret_cast<const float4*>(&attn[(r0 + row) * DD + c4 * 4]);
    *reinterpret_cast<ushort4*>(&s_a[row * 104 + c4 * 4]) = f4bf(a);
    *reinterpret_cast<float4*>(&s_x2[row * 84 + c4 * 4]) =
        *reinterpret_cast<const float4*>(&x[(r0 + row) * DD + c4 * 4]);
  }
  for (int k = 0; k < 4; ++k) {
    int idx = tid + k * 256;
    if (idx < 800) {
      int row = idx / 10, ch = idx % 10;
      *reinterpret_cast<uint4*>(&s_w[row * 104 + ch * 8]) =
          *reinterpret_cast<const uint4*>(&wo[row * DD + ch * 8]);
    }
  }
  if (tid < 128) {
    int row = tid >> 1, half = tid & 1;
    *reinterpret_cast<uint4*>(&s_a[row * 104 + 80 + half * 8]) = make_uint4(0,0,0,0);
  }
  if (tid < 160) {
    int row = tid >> 1, half = tid & 1;
    *reinterpret_cast<uint4*>(&s_w[row * 104 + 80 + half * 8]) = make_uint4(0,0,0,0);
  }
  __syncthreads();
  int w = tid >> 6, lane = tid & 63;
  int m = lane & 15, q = lane >> 4;
  f32x4 acc[5] = {};
#pragma unroll
  for (int kk = 0; kk < 3; ++kk) {
    bf16x8 a = *reinterpret_cast<const bf16x8*>(&s_a[(w * 16 + m) * 104 + kk * 32 + q * 8]);
#pragma unroll
    for (int c5 = 0; c5 < 5; ++c5) {
      bf16x8 b = *reinterpret_cast<const bf16x8*>(&s_w[(c5 * 16 + m) * 104 + kk * 32 + q * 8]);
      acc[c5] = __builtin_amdgcn_mfma_f32_16x16x32_bf16(a, b, acc[c5], 0, 0, 0);
    }
  }
  // v = acc + bo + x ; write res; row-LN (rows live within one wave: 16 lanes/row)
  float v[5][4];
  float sm[4] = {0.f, 0.f, 0.f, 0.f}, sq[4] = {0.f, 0.f, 0.f, 0.f};
#pragma unroll
  for (int c5 = 0; c5 < 5; ++c5) {
    int c = c5 * 16 + m;
    float bv = bo[c];
#pragma unroll
    for (int r = 0; r < 4; ++r) {
      int lrow = w * 16 + q * 4 + r;
      float t = acc[c5][r] + bv + s_x2[lrow * 84 + c];
      v[c5][r] = t;
      res[(r0 + lrow) * DD + c] = t;
      sm[r] += t; sq[r] += t * t;
    }
  }
#pragma unroll
  for (int r = 0; r < 4; ++r) {
#pragma unroll
    for (int d2 = 1; d2 < 16; d2 <<= 1) {
      sm[r] += __shfl_xor(sm[r], d2, 16);
      sq[r] += __shfl_xor(sq[r], d2, 16);
    }
  }
#pragma unroll
  for (int r = 0; r < 4; ++r) {
    float mu = sm[r] * (1.f / DD);
    float ri = rsqrtf(sq[r] * (1.f / DD) - mu * mu + EPSF);
    int lrow = w * 16 + q * 4 + r;
#pragma unroll
    for (int c5 = 0; c5 < 5; ++c5) {
      int c = c5 * 16 + m;
      ffln_bf[(r0 + lrow) * DD + c] = f2bf((v[c5][r] - mu) * ri * fg[c] + fb[c]);
    }
  }
}

// ---------------- D: FFN1 MFMA: h = relu(ffln @ W1^T + b1), bf16 out --------
// grid (ROWS/128, FFND/128), block 256
__global__ __launch_bounds__(256) void k_ffn1m(
    const unsigned short* __restrict__ A, const unsigned short* __restrict__ W,
    const float* __restrict__ b1, unsigned short* __restrict__ h) {
  __shared__ unsigned short s_a[128 * 104];
  __shared__ unsigned short s_b[128 * 104];
  int tid = threadIdx.x;
  int r0 = blockIdx.x * 128, c0 = blockIdx.y * 128;
  for (int k = 0; k < 5; ++k) {
    int idx = tid + k * 256;  // 1280 = 128 rows x 10 uint4
    int row = idx / 10, ch = idx % 10;
    *reinterpret_cast<uint4*>(&s_a[row * 104 + ch * 8]) =
        *reinterpret_cast<const uint4*>(&A[(r0 + row) * DD + ch * 8]);
    *reinterpret_cast<uint4*>(&s_b[row * 104 + ch * 8]) =
        *reinterpret_cast<const uint4*>(&W[(c0 + row) * DD + ch * 8]);
  }
  {
    int row = tid >> 1, half = tid & 1;
    uint4 z = make_uint4(0, 0, 0, 0);
    *reinterpret_cast<uint4*>(&s_a[row * 104 + 80 + half * 8]) = z;
    *reinterpret_cast<uint4*>(&s_b[row * 104 + 80 + half * 8]) = z;
  }
  __syncthreads();
  int w = tid >> 6, lane = tid & 63;
  int m = lane & 15, q = lane >> 4;
  f32x4 acc[2][8] = {};
#pragma unroll
  for (int kk = 0; kk < 3; ++kk) {
    bf16x8 a0 = *reinterpret_cast<const bf16x8*>(&s_a[(w * 32 + m) * 104 + kk * 32 + q * 8]);
    bf16x8 a1 = *reinterpret_cast<const bf16x8*>(&s_a[(w * 32 + 16 + m) * 104 + kk * 32 + q * 8]);
#pragma unroll
    for (int ct = 0; ct < 8; ++ct) {
      bf16x8 b = *reinterpret_cast<const bf16x8*>(&s_b[(ct * 16 + m) * 104 + kk * 32 + q * 8]);
      acc[0][ct] = __builtin_amdgcn_mfma_f32_16x16x32_bf16(a0, b, acc[0][ct], 0, 0, 0);
      acc[1][ct] = __builtin_amdgcn_mfma_f32_16x16x32_bf16(a1, b, acc[1][ct], 0, 0, 0);
    }
  }
#pragma unroll
  for (int rt = 0; rt < 2; ++rt)
#pragma unroll
    for (int ct = 0; ct < 8; ++ct) {
      int col = c0 + ct * 16 + m;
      float bias = b1[col];
#pragma unroll
      for (int r = 0; r < 4; ++r) {
        int grow = r0 + w * 32 + rt * 16 + q * 4 + r;
        h[grow * FFND + col] = f2bf(fmaxf(acc[rt][ct][r] + bias, 0.f));
      }
    }
}

// ---------------- E: FFN2 fused: x = LN(h @ W2^T + b2 + res) ----------------
// grid ROWS/16, block 320 (5 waves; wave w owns col-tile w). Full K=2048 in-block.
__global__ __launch_bounds__(320) void k_ffn2c(
    const unsigned short* __restrict__ h, const unsigned short* __restrict__ w2,
    const float* __restrict__ b2, const float* __restrict__ res,
    float* __restrict__ x, const float* __restrict__ og,
    const float* __restrict__ ob) {
  __shared__ unsigned short s_h[16 * 136];
  __shared__ unsigned short s_w[80 * 136];
  __shared__ float s_ps[5 * 16], s_pq[5 * 16], s_mu[16], s_ri[16];
  int tid = threadIdx.x;
  int r0 = blockIdx.x * 16;
  int w = tid >> 6, lane = tid & 63;
  int m = lane & 15, q = lane >> 4;
  f32x4 acc = {};
  for (int sub = 0; sub < 16; ++sub) {
    int kbase = sub * 128;
    __syncthreads();
    for (int k = 0; k < 5; ++k) {
      int idx = tid + k * 320;  // 1600 slots for 1536 loads
      if (idx < 256) {
        int row = idx >> 4, ch = idx & 15;
        *reinterpret_cast<uint4*>(&s_h[row * 136 + ch * 8]) =
            *reinterpret_cast<const uint4*>(&h[(r0 + row) * FFND + kbase + ch * 8]);
      } else if (idx < 1536) {
        int j = idx - 256;
        int row = j >> 4, ch = j & 15;
        *reinterpret_cast<uint4*>(&s_w[row * 136 + ch * 8]) =
            *reinterpret_cast<const uint4*>(&w2[row * FFND + kbase + ch * 8]);
      }
    }
    __syncthreads();
#pragma unroll
    for (int kk = 0; kk < 4; ++kk) {
      bf16x8 a = *reinterpret_cast<const bf16x8*>(&s_h[m * 136 + kk * 32 + q * 8]);
      bf16x8 b = *reinterpret_cast<const bf16x8*>(&s_w[(w * 16 + m) * 136 + kk * 32 + q * 8]);
      acc = __builtin_amdgcn_mfma_f32_16x16x32_bf16(a, b, acc, 0, 0, 0);
    }
  }
  // epilogue: v = acc + b2 + res; LN across 80 cols (5 waves) via LDS
  int c = w * 16 + m;
  float bv = b2[c];
  float v[4], psm[4], psq[4];
#pragma unroll
  for (int r = 0; r < 4; ++r) {
    int lrow = q * 4 + r;
    v[r] = acc[r] + bv + res[(r0 + lrow) * DD + c];
    psm[r] = v[r]; psq[r] = v[r] * v[r];
#pragma unroll
    for (int d2 = 1; d2 < 16; d2 <<= 1) {
      psm[r] += __shfl_xor(psm[r], d2, 16);
      psq[r] += __shfl_xor(psq[r], d2, 16);
    }
  }
  if (m == 0) {
#pragma unroll
    for (int r = 0; r < 4; ++r) {
      s_ps[w * 16 + q * 4 + r] = psm[r];
      s_pq[w * 16 + q * 4 + r] = psq[r];
    }
  }
  __syncthreads();
  if (tid < 16) {
    float sm = 0.f, sq = 0.f;
#pragma unroll
    for (int w5 = 0; w5 < 5; ++w5) { sm += s_ps[w5 * 16 + tid]; sq += s_pq[w5 * 16 + tid]; }
    float mu = sm * (1.f / DD);
    s_mu[tid] = mu;
    s_ri[tid] = rsqrtf(sq * (1.f / DD) - mu * mu + EPSF);
  }
  __syncthreads();
  float gv = og[c], bvo = ob[c];
#pragma unroll
  for (int r = 0; r < 4; ++r) {
    int lrow = q * 4 + r;
    x[(r0 + lrow) * DD + c] = (v[r] - s_mu[lrow]) * s_ri[lrow] * gv + bvo;
  }
}

// ---------------- P: final projection MFMA + lengths tail ----------------
// grid (2048/64, 768/64), block 256
__global__ __launch_bounds__(256) void k_projm(
    const float* __restrict__ x, const unsigned short* __restrict__ wp,
    const float* __restrict__ bp, const int* __restrict__ lengths,
    float* __restrict__ out) {
  __shared__ unsigned short s_a[64 * 104];
  __shared__ unsigned short s_w[64 * 104];
  int tid = threadIdx.x;
  int gr0 = blockIdx.x * 64;
  int c0 = blockIdx.y * 64;
  int b = gr0 / UU;
  int u0 = gr0 % UU;
  for (int k = 0; k < 5; ++k) {
    int idx = tid + k * 256;  // 1280
    int row = idx / 20, c4 = idx % 20;
    float4 a = *reinterpret_cast<const float4*>(&x[(b * KK + RCL + u0 + row) * DD + c4 * 4]);
    *reinterpret_cast<ushort4*>(&s_a[row * 104 + c4 * 4]) = f4bf(a);
  }
  for (int k = 0; k < 3; ++k) {
    int idx = tid + k * 256;
    if (idx < 640) {
      int row = idx / 10, ch = idx % 10;
      *reinterpret_cast<uint4*>(&s_w[row * 104 + ch * 8]) =
          *reinterpret_cast<const uint4*>(&wp[(c0 + row) * DD + ch * 8]);
    }
  }
  if (tid < 128) {
    int row = tid >> 1, half = tid & 1;
    uint4 z = make_uint4(0, 0, 0, 0);
    *reinterpret_cast<uint4*>(&s_a[row * 104 + 80 + half * 8]) = z;
    *reinterpret_cast<uint4*>(&s_w[row * 104 + 80 + half * 8]) = z;
  }
  __syncthreads();
  int w = tid >> 6, lane = tid & 63;
  int m = lane & 15, q = lane >> 4;
  f32x4 acc[4] = {};
#pragma unroll
  for (int kk = 0; kk < 3; ++kk) {
    bf16x8 a = *reinterpret_cast<const bf16x8*>(&s_a[(w * 16 + m) * 104 + kk * 32 + q * 8]);
#pragma unroll
    for (int ct = 0; ct < 4; ++ct) {
      bf16x8 bfr = *reinterpret_cast<const bf16x8*>(&s_w[(ct * 16 + m) * 104 + kk * 32 + q * 8]);
      acc[ct] = __builtin_amdgcn_mfma_f32_16x16x32_bf16(a, bfr, acc[ct], 0, 0, 0);
    }
  }
#pragma unroll
  for (int ct = 0; ct < 4; ++ct) {
    int c = c0 + ct * 16 + m;
    float bv = bp[c];
#pragma unroll
    for (int r = 0; r < 4; ++r) {
      int grow = gr0 + w * 16 + q * 4 + r;
      out[grow * OUTD + c] = acc[ct][r] + bv;
    }
  }
  if (blockIdx.x == 0 && blockIdx.y == 0 && tid < BB)
    out[BB * UU * OUTD + tid] = (float)lengths[tid];
}

extern "C" void kernel_launch(void* const* d_in, const int* in_sizes, int n_in,
                              void* d_out, int out_size, void* d_ws, size_t ws_size,
                              hipStream_t stream) {
  const float* mel   = (const float*)d_in[0];
  const float* lng   = (const float*)d_in[1];
  const float* lnb   = (const float*)d_in[2];
  const float* Wq    = (const float*)d_in[3];
  const float* bq    = (const float*)d_in[4];
  const float* Wkv   = (const float*)d_in[5];
  const float* bkv   = (const float*)d_in[6];
  const float* Wo    = (const float*)d_in[7];
  const float* bo    = (const float*)d_in[8];
  const float* ffg   = (const float*)d_in[9];
  const float* ffb   = (const float*)d_in[10];
  const float* W1    = (const float*)d_in[11];
  const float* b1    = (const float*)d_in[12];
  const float* W2    = (const float*)d_in[13];
  const float* b2    = (const float*)d_in[14];
  const float* og    = (const float*)d_in[15];
  const float* ob    = (const float*)d_in[16];
  const float* Wp    = (const float*)d_in[17];
  const float* bp    = (const float*)d_in[18];
  const int*   lens  = (const int*)d_in[19];
  float* out = (float*)d_out;

  // workspace layout. h_bf aliases qkv (qkv dead after k_attn; h dead before
  // next layer's k_qkvm writes qkv).
  float* ws   = (float*)d_ws;
  float* x    = ws;                             // 204800 f
  float* qkv  = x + ROWS * DD;                  // union start (614400 f used)
  unsigned short* h_bf = (unsigned short*)qkv;  // 5242880 sh = 2621440 f span
  float* attn = qkv + 2621440;                  // 204800 f
  float* res  = attn + ROWS * DD;               // 204800 f
  unsigned short* ffln_bf = (unsigned short*)(res + ROWS * DD);  // 204800 sh
  unsigned short* w1bf  = ffln_bf + ROWS * DD;        // 1966080 sh
  unsigned short* w2bf  = w1bf + LL * FFND * DD;      // 1966080 sh
  unsigned short* wqbf  = w2bf + LL * FFND * DD;      // 76800 sh
  unsigned short* wkvbf = wqbf + LL * DD * DD;        // 153600 sh
  unsigned short* wobf  = wkvbf + LL * 2 * DD * DD;   // 76800 sh
  unsigned short* wpbf  = wobf + LL * DD * DD;        // 61440 sh

  k_gather<<<(ROWS * DD + 255) / 256, 256, 0, stream>>>(mel, x);
  k_cvt<<<4200, 256, 0, stream>>>(W1, W2, Wq, Wkv, Wo, Wp,
                                  w1bf, w2bf, wqbf, wkvbf, wobf, wpbf);

  for (int l = 0; l < LL; ++l) {
    const unsigned short* lWq  = wqbf  + l * DD * DD;
    const unsigned short* lWkv = wkvbf + l * 2 * DD * DD;
    const unsigned short* lWo  = wobf  + l * DD * DD;
    const unsigned short* lW1  = w1bf  + l * FFND * DD;
    const unsigned short* lW2  = w2bf  + l * FFND * DD;

    k_qkvm<<<dim3(ROWS / 64, 3), 256, 0, stream>>>(
        x, qkv, lWq, bq + l * DD, lWkv, bkv + l * 2 * DD,
        lng + l * DD, lnb + l * DD);
    k_attn<<<dim3(NSEG, HH, BB), 64, 0, stream>>>(qkv, attn, lens);
    k_oprojm<<<ROWS / 64, 256, 0, stream>>>(
        attn, lWo, bo + l * DD, x, res, ffln_bf, ffg + l * DD, ffb + l * DD);
    k_ffn1m<<<dim3(ROWS / 128, FFND / 128), 256, 0, stream>>>(
        ffln_bf, lW1, b1 + l * FFND, h_bf);
    k_ffn2c<<<ROWS / 16, 320, 0, stream>>>(
        h_bf, lW2, b2 + l * DD, res, x, og + l * DD, ob + l * DD);
  }

  k_projm<<<dim3(BB * UU / 64, OUTD / 64), 256, 0, stream>>>(x, wpbf, bp, lens, out);
}

// Round 4
// 932.221 us; speedup vs baseline: 1.2484x; 1.2484x over previous
//
#include <hip/hip_runtime.h>
#include <math.h>

#define BB 4
#define UU 512
#define DD 80
#define HH 8
#define FFND 2048
#define LL 12
#define SEGC 32
#define LCC 50
#define RCC 8
#define NSEG 16
#define RCL 128
#define KK 640
#define ROWS (BB*KK)        // 2560
#define OUTD 768
#define EPSF 1e-5f
#define SCALEF 0.31622776601683794f  // (D/H)^-0.5

typedef __attribute__((ext_vector_type(8))) short bf16x8;
typedef __attribute__((ext_vector_type(4))) float f32x4;

__device__ inline unsigned short f2bf(float f) {
  unsigned int u = __float_as_uint(f);
  u += 0x7fffu + ((u >> 16) & 1u);
  return (unsigned short)(u >> 16);
}
__device__ inline ushort4 f4bf(float4 v) {
  ushort4 r;
  r.x = f2bf(v.x); r.y = f2bf(v.y); r.z = f2bf(v.z); r.w = f2bf(v.w);
  return r;
}
__device__ inline bf16x8 bz8() {
  bf16x8 r = {0, 0, 0, 0, 0, 0, 0, 0};
  return r;
}
// A/B fragment from fp32 row (K=80, zero-padded to 96)
__device__ inline bf16x8 fragf32(const float* __restrict__ rowp, int k) {
  if (k < 80) {
    float4 a = *reinterpret_cast<const float4*>(rowp + k);
    float4 b = *reinterpret_cast<const float4*>(rowp + k + 4);
    bf16x8 r;
    r[0] = (short)f2bf(a.x); r[1] = (short)f2bf(a.y);
    r[2] = (short)f2bf(a.z); r[3] = (short)f2bf(a.w);
    r[4] = (short)f2bf(b.x); r[5] = (short)f2bf(b.y);
    r[6] = (short)f2bf(b.z); r[7] = (short)f2bf(b.w);
    return r;
  }
  return bz8();
}
// B fragment from bf16 row (K=80, zero-padded to 96)
__device__ inline bf16x8 fragbf(const unsigned short* __restrict__ rowp, int k) {
  if (k < 80) return *reinterpret_cast<const bf16x8*>(rowp + k);
  return bz8();
}

// ---------------- gather: x0 = concat(rc, utt) ----------------
__global__ __launch_bounds__(256) void k_gather(const float* __restrict__ mel,
                                                float* __restrict__ x) {
  int idx = blockIdx.x * 256 + threadIdx.x;
  if (idx >= ROWS * DD) return;
  int d = idx % DD;
  int row = idx / DD;
  int b = row / KK;
  int j = row % KK;
  int pos;
  if (j < RCL) {
    int i = j >> 3, r = j & 7;
    pos = (i < NSEG - 1) ? (i + 1) * SEGC + r : UU + r;
  } else {
    pos = j - RCL;
  }
  x[idx] = mel[(b * (UU + RCC) + pos) * DD + d];
}

// ---------------- convert ALL weights fp32 -> bf16 ----------------
__global__ __launch_bounds__(256) void k_cvt(
    const float* __restrict__ W1, const float* __restrict__ W2,
    const float* __restrict__ Wq, const float* __restrict__ Wkv,
    const float* __restrict__ Wo, const float* __restrict__ Wp,
    unsigned short* __restrict__ o1, unsigned short* __restrict__ o2,
    unsigned short* __restrict__ oq, unsigned short* __restrict__ okv,
    unsigned short* __restrict__ oo, unsigned short* __restrict__ op) {
  int t = blockIdx.x * 256 + threadIdx.x;
  const float* src; unsigned short* dst; int i;
  if (t < 491520)       { src = W1;  dst = o1;  i = t; }
  else if (t < 983040)  { src = W2;  dst = o2;  i = t - 491520; }
  else if (t < 1002240) { src = Wq;  dst = oq;  i = t - 983040; }
  else if (t < 1040640) { src = Wkv; dst = okv; i = t - 1002240; }
  else if (t < 1059840) { src = Wo;  dst = oo;  i = t - 1040640; }
  else                  { src = Wp;  dst = op;  i = t - 1059840; }
  float4 v = reinterpret_cast<const float4*>(src)[i];
  reinterpret_cast<ushort4*>(dst)[i] = f4bf(v);
}

// ---------------- S1: LN_in + QKV GEMM, one wave per (16 rows, ct) ----------
// grid (ROWS/16, 3) = 480 blocks, block 64
__global__ __launch_bounds__(64) void k_qkv2(
    const float* __restrict__ x, float* __restrict__ qkv,
    const unsigned short* __restrict__ wq, const float* __restrict__ bq,
    const unsigned short* __restrict__ wkv, const float* __restrict__ bkv,
    const float* __restrict__ lg, const float* __restrict__ lb) {
  __shared__ unsigned short s_xn[16 * 104];
  int lane = threadIdx.x;
  int r0 = blockIdx.x * 16;
  int ct = blockIdx.y;
  int m = lane & 15, q = lane >> 4;
  // LN: lane handles row m, col part q (20 cols); stats via shuffles
  {
    const float* xr = &x[(r0 + m) * DD + q * 20];
    float4 v4[5];
    float sm = 0.f, sq = 0.f;
#pragma unroll
    for (int j = 0; j < 5; ++j) {
      v4[j] = *reinterpret_cast<const float4*>(xr + j * 4);
      sm += v4[j].x + v4[j].y + v4[j].z + v4[j].w;
      sq += v4[j].x * v4[j].x + v4[j].y * v4[j].y +
            v4[j].z * v4[j].z + v4[j].w * v4[j].w;
    }
    sm += __shfl_xor(sm, 16); sq += __shfl_xor(sq, 16);
    sm += __shfl_xor(sm, 32); sq += __shfl_xor(sq, 32);
    float mu = sm * (1.f / DD);
    float ri = rsqrtf(sq * (1.f / DD) - mu * mu + EPSF);
#pragma unroll
    for (int j = 0; j < 5; ++j) {
      int c = q * 20 + j * 4;
      float4 v = v4[j];
      v.x = (v.x - mu) * ri * lg[c] + lb[c];
      v.y = (v.y - mu) * ri * lg[c + 1] + lb[c + 1];
      v.z = (v.z - mu) * ri * lg[c + 2] + lb[c + 2];
      v.w = (v.w - mu) * ri * lg[c + 3] + lb[c + 3];
      *reinterpret_cast<ushort4*>(&s_xn[m * 104 + c]) = f4bf(v);
    }
    if (q == 0) {
      *reinterpret_cast<uint4*>(&s_xn[m * 104 + 80]) = make_uint4(0, 0, 0, 0);
      *reinterpret_cast<uint4*>(&s_xn[m * 104 + 88]) = make_uint4(0, 0, 0, 0);
      *reinterpret_cast<uint4*>(&s_xn[m * 104 + 96]) = make_uint4(0, 0, 0, 0);
    }
  }
  __syncthreads();
  const unsigned short* wb = (ct == 0) ? wq : (ct == 1 ? wkv : wkv + 80 * DD);
  const float* bias = (ct == 0) ? bq : (bkv + (ct == 2 ? 80 : 0));
  bf16x8 a[3];
#pragma unroll
  for (int kk = 0; kk < 3; ++kk)
    a[kk] = *reinterpret_cast<const bf16x8*>(&s_xn[m * 104 + kk * 32 + q * 8]);
  f32x4 acc[5] = {};
#pragma unroll
  for (int t = 0; t < 5; ++t) {
    const unsigned short* wr = &wb[(t * 16 + m) * DD];
#pragma unroll
    for (int kk = 0; kk < 3; ++kk) {
      bf16x8 b = fragbf(wr, kk * 32 + q * 8);
      acc[t] = __builtin_amdgcn_mfma_f32_16x16x32_bf16(a[kk], b, acc[t], 0, 0, 0);
    }
  }
#pragma unroll
  for (int t = 0; t < 5; ++t) {
    int c = t * 16 + m;
    float bv = bias[c];
#pragma unroll
    for (int r = 0; r < 4; ++r)
      qkv[(r0 + q * 4 + r) * 240 + ct * 80 + c] = acc[t][r] + bv;
  }
}

// ---------------- S2: masked segmented attention ----------------
// grid (NSEG, H, B), block 64
__global__ __launch_bounds__(64) void k_attn(const float* __restrict__ qkv,
                                             float* __restrict__ attn,
                                             const int* __restrict__ lengths) {
  int i = blockIdx.x, h = blockIdx.y, b = blockIdx.z;
  int tid = threadIdx.x;
  int s = i * SEGC - LCC; if (s < 0) s = 0;
  int e = (i + 1) * SEGC;
  int nk = RCC + (e - s);  // 40..90
  __shared__ float s_k[10 * 97], s_v[10 * 97], s_q[10 * 44];
  __shared__ float s_p[40 * 91], s_kb[90], s_den[40];
  int len = lengths[b];
  for (int j = tid; j < nk; j += 64) {
    int kr = (j < RCC) ? i * RCC + j : RCL + s + (j - RCC);
    const float* kp = &qkv[(b * KK + kr) * 240 + 80 + h * 10];
#pragma unroll
    for (int d = 0; d < 10; ++d) {
      s_k[d * 97 + j] = kp[d];
      s_v[d * 97 + j] = kp[80 + d];
    }
    s_kb[j] = (kr >= len + RCL) ? -1e8f : 0.f;
  }
  if (tid < 40) {
    int qr = (tid < RCC) ? i * RCC + tid : RCL + i * SEGC + (tid - RCC);
    const float* qp = &qkv[(b * KK + qr) * 240 + h * 10];
#pragma unroll
    for (int d = 0; d < 10; ++d) s_q[d * 44 + tid] = qp[d];
  }
  __syncthreads();
  for (int q = 0; q < 40; ++q) {
    for (int jk = tid; jk < nk; jk += 64) {
      float dot = 0.f;
#pragma unroll
      for (int d = 0; d < 10; ++d) dot += s_q[d * 44 + q] * s_k[d * 97 + jk];
      s_p[q * 91 + jk] = dot * SCALEF + s_kb[jk];
    }
  }
  __syncthreads();
  if (tid < 40) {
    float mx = -1e30f;
    for (int kx = 0; kx < nk; ++kx) mx = fmaxf(mx, s_p[tid * 91 + kx]);
    float sum = 0.f;
    for (int kx = 0; kx < nk; ++kx) {
      float ev = __expf(s_p[tid * 91 + kx] - mx);
      s_p[tid * 91 + kx] = ev;
      sum += ev;
    }
    s_den[tid] = 1.f / sum;
  }
  __syncthreads();
  int d = tid & 15, qoff = tid >> 4;
  if (d < 10) {
    for (int pass = 0; pass < 10; ++pass) {
      int q = pass * 4 + qoff;
      float o = 0.f;
      for (int kx = 0; kx < nk; ++kx) o += s_p[q * 91 + kx] * s_v[d * 97 + kx];
      int qr = (q < RCC) ? i * RCC + q : RCL + i * SEGC + (q - RCC);
      attn[(b * KK + qr) * DD + h * 10 + d] = o * s_den[q];
    }
  }
}

// ---------------- S3: fused tail: oproj+LN_ff+FFN1+relu+FFN2+res+LN_out -----
// grid ROWS/16 = 160, block 256 (4 waves). Row-local; x updated in place.
__global__ __launch_bounds__(256) void k_tail(
    const float* __restrict__ attn, const unsigned short* __restrict__ wo,
    const float* __restrict__ bo, const unsigned short* __restrict__ w1,
    const float* __restrict__ b1, const unsigned short* __restrict__ w2,
    const float* __restrict__ b2, const float* __restrict__ fg,
    const float* __restrict__ fb, const float* __restrict__ og,
    const float* __restrict__ ob, float* __restrict__ x) {
  __shared__ unsigned short s_hw[4 * 16 * 136];  // per-wave h strip (128 cols)
  __shared__ float s_part[4 * 16 * 84];          // per-wave FFN2 K-partials
  __shared__ float s_v[16 * 84];                 // oproj out (res), later v2
  __shared__ unsigned short s_f[16 * 104];       // ffln bf16 (K-padded)
  __shared__ float s_mu[16], s_ri[16];
  int tid = threadIdx.x;
  int r0 = blockIdx.x * 16;
  int w = tid >> 6, lane = tid & 63;
  int m = lane & 15, q = lane >> 4;

  // ---- oproj: out[16x80] = attn_bf @ Wo^T; B-frags direct from global ----
  bf16x8 af[3];
#pragma unroll
  for (int kk = 0; kk < 3; ++kk)
    af[kk] = fragf32(&attn[(r0 + m) * DD], kk * 32 + q * 8);
  f32x4 o0 = {};
#pragma unroll
  for (int kk = 0; kk < 3; ++kk) {
    bf16x8 b = fragbf(&wo[(w * 16 + m) * DD], kk * 32 + q * 8);
    o0 = __builtin_amdgcn_mfma_f32_16x16x32_bf16(af[kk], b, o0, 0, 0, 0);
  }
  f32x4 o1 = {};
  if (w == 0) {
#pragma unroll
    for (int kk = 0; kk < 3; ++kk) {
      bf16x8 b = fragbf(&wo[(64 + m) * DD], kk * 32 + q * 8);
      o1 = __builtin_amdgcn_mfma_f32_16x16x32_bf16(af[kk], b, o1, 0, 0, 0);
    }
  }
  {
    int c = w * 16 + m;
    float bv = bo[c];
#pragma unroll
    for (int r = 0; r < 4; ++r) {
      int lrow = q * 4 + r;
      s_v[lrow * 84 + c] = o0[r] + bv + x[(r0 + lrow) * DD + c];
    }
    if (w == 0) {
      int c4 = 64 + m;
      float bv4 = bo[c4];
#pragma unroll
      for (int r = 0; r < 4; ++r) {
        int lrow = q * 4 + r;
        s_v[lrow * 84 + c4] = o1[r] + bv4 + x[(r0 + lrow) * DD + c4];
      }
    }
  }
  __syncthreads();
  // ---- LN_ff stats (wave 0) ----
  if (tid < 64) {
    int row = tid & 15, part = tid >> 4;
    float sm = 0.f, sq = 0.f;
    for (int j = 0; j < 20; ++j) {
      float v = s_v[row * 84 + part * 20 + j];
      sm += v; sq += v * v;
    }
    sm += __shfl_xor(sm, 16); sq += __shfl_xor(sq, 16);
    sm += __shfl_xor(sm, 32); sq += __shfl_xor(sq, 32);
    if (part == 0) {
      float mu = sm * (1.f / DD);
      s_mu[row] = mu;
      s_ri[row] = rsqrtf(sq * (1.f / DD) - mu * mu + EPSF);
    }
  }
  __syncthreads();
  // ---- ffln bf16 into s_f ----
  {
    int row = tid >> 4, cg = tid & 15;
    float mu = s_mu[row], ri = s_ri[row];
#pragma unroll
    for (int j = 0; j < 5; ++j) {
      int c = cg * 5 + j;
      s_f[row * 104 + c] = f2bf((s_v[row * 84 + c] - mu) * ri * fg[c] + fb[c]);
    }
    if (cg == 15)
      for (int c = 80; c < 104; ++c) s_f[row * 104 + c] = 0;
  }
  __syncthreads();
  // ---- FFN1+FFN2, K-split: wave w owns hidden cols [512w, 512w+512) ----
  bf16x8 ff[3];
#pragma unroll
  for (int kk = 0; kk < 3; ++kk)
    ff[kk] = *reinterpret_cast<const bf16x8*>(&s_f[m * 104 + kk * 32 + q * 8]);
  f32x4 acc2[5] = {};
  unsigned short* hw = &s_hw[w * (16 * 136)];
  int c0w = w * 512;
  for (int sc = 0; sc < 4; ++sc) {
    int cc = c0w + sc * 128;
    // FFN1 for 128 cols -> hw (in-wave, no barrier)
#pragma unroll
    for (int t = 0; t < 8; ++t) {
      int col = cc + t * 16 + m;
      f32x4 a1 = {};
#pragma unroll
      for (int kk = 0; kk < 3; ++kk) {
        bf16x8 b = fragbf(&w1[col * DD], kk * 32 + q * 8);
        a1 = __builtin_amdgcn_mfma_f32_16x16x32_bf16(ff[kk], b, a1, 0, 0, 0);
      }
      float bb = b1[col];
#pragma unroll
      for (int r = 0; r < 4; ++r)
        hw[(q * 4 + r) * 136 + t * 16 + m] = f2bf(fmaxf(a1[r] + bb, 0.f));
    }
    // FFN2 partial over this 128-K chunk (reads hw transposed, in-wave)
#pragma unroll
    for (int kk2 = 0; kk2 < 4; ++kk2) {
      bf16x8 ah = *reinterpret_cast<const bf16x8*>(&hw[m * 136 + kk2 * 32 + q * 8]);
#pragma unroll
      for (int t = 0; t < 5; ++t) {
        bf16x8 b = *reinterpret_cast<const bf16x8*>(
            &w2[(t * 16 + m) * FFND + cc + kk2 * 32 + q * 8]);
        acc2[t] = __builtin_amdgcn_mfma_f32_16x16x32_bf16(ah, b, acc2[t], 0, 0, 0);
      }
    }
  }
#pragma unroll
  for (int t = 0; t < 5; ++t)
#pragma unroll
    for (int r = 0; r < 4; ++r)
      s_part[w * (16 * 84) + (q * 4 + r) * 84 + t * 16 + m] = acc2[t][r];
  __syncthreads();
  // ---- reduce K-partials + b2 + residual -> v2 (in-place in s_v) ----
  {
    int row = tid >> 4, cg = tid & 15;
#pragma unroll
    for (int j = 0; j < 5; ++j) {
      int c = cg * 5 + j;
      int o = row * 84 + c;
      float v = s_part[o] + s_part[16 * 84 + o] + s_part[2 * 16 * 84 + o] +
                s_part[3 * 16 * 84 + o] + b2[c] + s_v[o];
      s_v[o] = v;
    }
  }
  __syncthreads();
  // ---- LN_out stats ----
  if (tid < 64) {
    int row = tid & 15, part = tid >> 4;
    float sm = 0.f, sq = 0.f;
    for (int j = 0; j < 20; ++j) {
      float v = s_v[row * 84 + part * 20 + j];
      sm += v; sq += v * v;
    }
    sm += __shfl_xor(sm, 16); sq += __shfl_xor(sq, 16);
    sm += __shfl_xor(sm, 32); sq += __shfl_xor(sq, 32);
    if (part == 0) {
      float mu = sm * (1.f / DD);
      s_mu[row] = mu;
      s_ri[row] = rsqrtf(sq * (1.f / DD) - mu * mu + EPSF);
    }
  }
  __syncthreads();
  {
    int row = tid >> 4, cg = tid & 15;
    float mu = s_mu[row], ri = s_ri[row];
#pragma unroll
    for (int j = 0; j < 5; ++j) {
      int c = cg * 5 + j;
      x[(r0 + row) * DD + c] = (s_v[row * 84 + c] - mu) * ri * og[c] + ob[c];
    }
  }
}

// ---------------- P: final projection MFMA + lengths tail ----------------
// grid (2048/64, 768/64), block 256
__global__ __launch_bounds__(256) void k_projm(
    const float* __restrict__ x, const unsigned short* __restrict__ wp,
    const float* __restrict__ bp, const int* __restrict__ lengths,
    float* __restrict__ out) {
  __shared__ unsigned short s_a[64 * 104];
  __shared__ unsigned short s_w[64 * 104];
  int tid = threadIdx.x;
  int gr0 = blockIdx.x * 64;
  int c0 = blockIdx.y * 64;
  int b = gr0 / UU;
  int u0 = gr0 % UU;
  for (int k = 0; k < 5; ++k) {
    int idx = tid + k * 256;  // 1280
    int row = idx / 20, c4 = idx % 20;
    float4 a = *reinterpret_cast<const float4*>(&x[(b * KK + RCL + u0 + row) * DD + c4 * 4]);
    *reinterpret_cast<ushort4*>(&s_a[row * 104 + c4 * 4]) = f4bf(a);
  }
  for (int k = 0; k < 3; ++k) {
    int idx = tid + k * 256;
    if (idx < 640) {
      int row = idx / 10, ch = idx % 10;
      *reinterpret_cast<uint4*>(&s_w[row * 104 + ch * 8]) =
          *reinterpret_cast<const uint4*>(&wp[(c0 + row) * DD + ch * 8]);
    }
  }
  if (tid < 128) {
    int row = tid >> 1, half = tid & 1;
    uint4 z = make_uint4(0, 0, 0, 0);
    *reinterpret_cast<uint4*>(&s_a[row * 104 + 80 + half * 8]) = z;
    *reinterpret_cast<uint4*>(&s_w[row * 104 + 80 + half * 8]) = z;
  }
  __syncthreads();
  int w = tid >> 6, lane = tid & 63;
  int m = lane & 15, q = lane >> 4;
  f32x4 acc[4] = {};
#pragma unroll
  for (int kk = 0; kk < 3; ++kk) {
    bf16x8 a = *reinterpret_cast<const bf16x8*>(&s_a[(w * 16 + m) * 104 + kk * 32 + q * 8]);
#pragma unroll
    for (int ct = 0; ct < 4; ++ct) {
      bf16x8 bfr = *reinterpret_cast<const bf16x8*>(&s_w[(ct * 16 + m) * 104 + kk * 32 + q * 8]);
      acc[ct] = __builtin_amdgcn_mfma_f32_16x16x32_bf16(a, bfr, acc[ct], 0, 0, 0);
    }
  }
#pragma unroll
  for (int ct = 0; ct < 4; ++ct) {
    int c = c0 + ct * 16 + m;
    float bv = bp[c];
#pragma unroll
    for (int r = 0; r < 4; ++r) {
      int grow = gr0 + w * 16 + q * 4 + r;
      out[grow * OUTD + c] = acc[ct][r] + bv;
    }
  }
  if (blockIdx.x == 0 && blockIdx.y == 0 && tid < BB)
    out[BB * UU * OUTD + tid] = (float)lengths[tid];
}

extern "C" void kernel_launch(void* const* d_in, const int* in_sizes, int n_in,
                              void* d_out, int out_size, void* d_ws, size_t ws_size,
                              hipStream_t stream) {
  const float* mel   = (const float*)d_in[0];
  const float* lng   = (const float*)d_in[1];
  const float* lnb   = (const float*)d_in[2];
  const float* Wq    = (const float*)d_in[3];
  const float* bq    = (const float*)d_in[4];
  const float* Wkv   = (const float*)d_in[5];
  const float* bkv   = (const float*)d_in[6];
  const float* Wo    = (const float*)d_in[7];
  const float* bo    = (const float*)d_in[8];
  const float* ffg   = (const float*)d_in[9];
  const float* ffb   = (const float*)d_in[10];
  const float* W1    = (const float*)d_in[11];
  const float* b1    = (const float*)d_in[12];
  const float* W2    = (const float*)d_in[13];
  const float* b2    = (const float*)d_in[14];
  const float* og    = (const float*)d_in[15];
  const float* ob    = (const float*)d_in[16];
  const float* Wp    = (const float*)d_in[17];
  const float* bp    = (const float*)d_in[18];
  const int*   lens  = (const int*)d_in[19];
  float* out = (float*)d_out;

  float* ws   = (float*)d_ws;
  float* x    = ws;                    // 204800 f
  float* qkv  = x + ROWS * DD;         // 614400 f
  float* attn = qkv + ROWS * 240;      // 204800 f
  unsigned short* w1bf  = (unsigned short*)(attn + ROWS * DD);  // 1966080 sh
  unsigned short* w2bf  = w1bf + LL * FFND * DD;                // 1966080 sh
  unsigned short* wqbf  = w2bf + LL * FFND * DD;                // 76800 sh
  unsigned short* wkvbf = wqbf + LL * DD * DD;                  // 153600 sh
  unsigned short* wobf  = wkvbf + LL * 2 * DD * DD;             // 76800 sh
  unsigned short* wpbf  = wobf + LL * DD * DD;                  // 61440 sh

  k_gather<<<800, 256, 0, stream>>>(mel, x);
  k_cvt<<<4200, 256, 0, stream>>>(W1, W2, Wq, Wkv, Wo, Wp,
                                  w1bf, w2bf, wqbf, wkvbf, wobf, wpbf);

  for (int l = 0; l < LL; ++l) {
    k_qkv2<<<dim3(ROWS / 16, 3), 64, 0, stream>>>(
        x, qkv, wqbf + l * DD * DD, bq + l * DD,
        wkvbf + l * 2 * DD * DD, bkv + l * 2 * DD,
        lng + l * DD, lnb + l * DD);
    k_attn<<<dim3(NSEG, HH, BB), 64, 0, stream>>>(qkv, attn, lens);
    k_tail<<<ROWS / 16, 256, 0, stream>>>(
        attn, wobf + l * DD * DD, bo + l * DD,
        w1bf + l * FFND * DD, b1 + l * FFND,
        w2bf + l * FFND * DD, b2 + l * DD,
        ffg + l * DD, ffb + l * DD, og + l * DD, ob + l * DD, x);
  }

  k_projm<<<dim3(BB * UU / 64, OUTD / 64), 256, 0, stream>>>(x, wpbf, bp, lens, out);
}

// Round 5
// 887.012 us; speedup vs baseline: 1.3120x; 1.0510x over previous
//
#include <hip/hip_runtime.h>
#include <math.h>

#define BB 4
#define UU 512
#define DD 80
#define HH 8
#define FFND 2048
#define LL 12
#define SEGC 32
#define LCC 50
#define RCC 8
#define NSEG 16
#define RCL 128
#define KK 640
#define ROWS (BB*KK)        // 2560
#define OUTD 768
#define EPSF 1e-5f
#define SCALEF 0.31622776601683794f  // (D/H)^-0.5

typedef __attribute__((ext_vector_type(8))) short bf16x8;
typedef __attribute__((ext_vector_type(4))) float f32x4;

__device__ inline unsigned short f2bf(float f) {
  unsigned int u = __float_as_uint(f);
  u += 0x7fffu + ((u >> 16) & 1u);
  return (unsigned short)(u >> 16);
}
__device__ inline ushort4 f4bf(float4 v) {
  ushort4 r;
  r.x = f2bf(v.x); r.y = f2bf(v.y); r.z = f2bf(v.z); r.w = f2bf(v.w);
  return r;
}
__device__ inline bf16x8 bz8() {
  bf16x8 r = {0, 0, 0, 0, 0, 0, 0, 0};
  return r;
}
__device__ inline bf16x8 fragf32(const float* __restrict__ rowp, int k) {
  if (k < 80) {
    float4 a = *reinterpret_cast<const float4*>(rowp + k);
    float4 b = *reinterpret_cast<const float4*>(rowp + k + 4);
    bf16x8 r;
    r[0] = (short)f2bf(a.x); r[1] = (short)f2bf(a.y);
    r[2] = (short)f2bf(a.z); r[3] = (short)f2bf(a.w);
    r[4] = (short)f2bf(b.x); r[5] = (short)f2bf(b.y);
    r[6] = (short)f2bf(b.z); r[7] = (short)f2bf(b.w);
    return r;
  }
  return bz8();
}
__device__ inline bf16x8 fragbf(const unsigned short* __restrict__ rowp, int k) {
  if (k < 80) return *reinterpret_cast<const bf16x8*>(rowp + k);
  return bz8();
}

// ---------------- gather ----------------
__global__ __launch_bounds__(256) void k_gather(const float* __restrict__ mel,
                                                float* __restrict__ x) {
  int idx = blockIdx.x * 256 + threadIdx.x;
  if (idx >= ROWS * DD) return;
  int d = idx % DD;
  int row = idx / DD;
  int b = row / KK;
  int j = row % KK;
  int pos;
  if (j < RCL) {
    int i = j >> 3, r = j & 7;
    pos = (i < NSEG - 1) ? (i + 1) * SEGC + r : UU + r;
  } else {
    pos = j - RCL;
  }
  x[idx] = mel[(b * (UU + RCC) + pos) * DD + d];
}

// ---------------- weights fp32 -> bf16 ----------------
__global__ __launch_bounds__(256) void k_cvt(
    const float* __restrict__ W1, const float* __restrict__ W2,
    const float* __restrict__ Wq, const float* __restrict__ Wkv,
    const float* __restrict__ Wo, const float* __restrict__ Wp,
    unsigned short* __restrict__ o1, unsigned short* __restrict__ o2,
    unsigned short* __restrict__ oq, unsigned short* __restrict__ okv,
    unsigned short* __restrict__ oo, unsigned short* __restrict__ op) {
  int t = blockIdx.x * 256 + threadIdx.x;
  const float* src; unsigned short* dst; int i;
  if (t < 491520)       { src = W1;  dst = o1;  i = t; }
  else if (t < 983040)  { src = W2;  dst = o2;  i = t - 491520; }
  else if (t < 1002240) { src = Wq;  dst = oq;  i = t - 983040; }
  else if (t < 1040640) { src = Wkv; dst = okv; i = t - 1002240; }
  else if (t < 1059840) { src = Wo;  dst = oo;  i = t - 1040640; }
  else                  { src = Wp;  dst = op;  i = t - 1059840; }
  float4 v = reinterpret_cast<const float4*>(src)[i];
  reinterpret_cast<ushort4*>(dst)[i] = f4bf(v);
}

// ---------------- S1: LN_in + QKV, one wave per 16x16 tile -------------------
// grid (ROWS/16, 15) = 2400 blocks, block 64
__global__ __launch_bounds__(64) void k_qkvt(
    const float* __restrict__ x, float* __restrict__ qkv,
    const unsigned short* __restrict__ wq, const float* __restrict__ bq,
    const unsigned short* __restrict__ wkv, const float* __restrict__ bkv,
    const float* __restrict__ lg, const float* __restrict__ lb) {
  int lane = threadIdx.x;
  int r0 = blockIdx.x * 16;
  int c0 = blockIdx.y * 16;  // global col in [0,240)
  int m = lane & 15, q = lane >> 4;
  // load this lane's A elements (row r0+m, k = kk*32+q*8 .. +7), fp32
  const float* xr = &x[(r0 + m) * DD];
  float xv[3][8];
  float sm = 0.f, sq = 0.f;
#pragma unroll
  for (int kk = 0; kk < 3; ++kk) {
    int base = kk * 32 + q * 8;
    if (base < 80) {
      float4 a = *reinterpret_cast<const float4*>(xr + base);
      float4 b = *reinterpret_cast<const float4*>(xr + base + 4);
      xv[kk][0] = a.x; xv[kk][1] = a.y; xv[kk][2] = a.z; xv[kk][3] = a.w;
      xv[kk][4] = b.x; xv[kk][5] = b.y; xv[kk][6] = b.z; xv[kk][7] = b.w;
#pragma unroll
      for (int j = 0; j < 8; ++j) { sm += xv[kk][j]; sq += xv[kk][j] * xv[kk][j]; }
    } else {
#pragma unroll
      for (int j = 0; j < 8; ++j) xv[kk][j] = 0.f;
    }
  }
  sm += __shfl_xor(sm, 16); sq += __shfl_xor(sq, 16);
  sm += __shfl_xor(sm, 32); sq += __shfl_xor(sq, 32);
  float mu = sm * (1.f / DD);
  float ri = rsqrtf(sq * (1.f / DD) - mu * mu + EPSF);
  // normalize -> bf16 A-frags
  bf16x8 a[3];
#pragma unroll
  for (int kk = 0; kk < 3; ++kk) {
    int base = kk * 32 + q * 8;
    if (base < 80) {
      float4 g1 = *reinterpret_cast<const float4*>(lg + base);
      float4 g2 = *reinterpret_cast<const float4*>(lg + base + 4);
      float4 b1v = *reinterpret_cast<const float4*>(lb + base);
      float4 b2v = *reinterpret_cast<const float4*>(lb + base + 4);
      float gg[8] = {g1.x, g1.y, g1.z, g1.w, g2.x, g2.y, g2.z, g2.w};
      float bb[8] = {b1v.x, b1v.y, b1v.z, b1v.w, b2v.x, b2v.y, b2v.z, b2v.w};
#pragma unroll
      for (int j = 0; j < 8; ++j)
        a[kk][j] = (short)f2bf((xv[kk][j] - mu) * ri * gg[j] + bb[j]);
    } else {
      a[kk] = bz8();
    }
  }
  // B-frags: weight row for global col c0+m
  int c = c0 + m;
  const unsigned short* wr = (c < 80) ? &wq[c * DD] : &wkv[(c - 80) * DD];
  f32x4 acc = {};
#pragma unroll
  for (int kk = 0; kk < 3; ++kk) {
    bf16x8 b = fragbf(wr, kk * 32 + q * 8);
    acc = __builtin_amdgcn_mfma_f32_16x16x32_bf16(a[kk], b, acc, 0, 0, 0);
  }
  float bv = (c < 80) ? bq[c] : bkv[c - 80];
#pragma unroll
  for (int r = 0; r < 4; ++r)
    qkv[(r0 + q * 4 + r) * 240 + c] = acc[r] + bv;
}

// ---------------- S2: masked segmented attention ----------------
// grid (NSEG, H, B), block 64
__global__ __launch_bounds__(64) void k_attn(const float* __restrict__ qkv,
                                             float* __restrict__ attn,
                                             const int* __restrict__ lengths) {
  int i = blockIdx.x, h = blockIdx.y, b = blockIdx.z;
  int tid = threadIdx.x;
  int s = i * SEGC - LCC; if (s < 0) s = 0;
  int e = (i + 1) * SEGC;
  int nk = RCC + (e - s);  // 40..90
  __shared__ float s_k[10 * 97], s_v[10 * 97], s_q[10 * 44];
  __shared__ float s_p[40 * 91], s_kb[90], s_den[40];
  int len = lengths[b];
  for (int j = tid; j < nk; j += 64) {
    int kr = (j < RCC) ? i * RCC + j : RCL + s + (j - RCC);
    const float* kp = &qkv[(b * KK + kr) * 240 + 80 + h * 10];
#pragma unroll
    for (int d = 0; d < 10; ++d) {
      s_k[d * 97 + j] = kp[d];
      s_v[d * 97 + j] = kp[80 + d];
    }
    s_kb[j] = (kr >= len + RCL) ? -1e8f : 0.f;
  }
  if (tid < 40) {
    int qr = (tid < RCC) ? i * RCC + tid : RCL + i * SEGC + (tid - RCC);
    const float* qp = &qkv[(b * KK + qr) * 240 + h * 10];
#pragma unroll
    for (int d = 0; d < 10; ++d) s_q[d * 44 + tid] = qp[d];
  }
  __syncthreads();
  for (int q = 0; q < 40; ++q) {
    for (int jk = tid; jk < nk; jk += 64) {
      float dot = 0.f;
#pragma unroll
      for (int d = 0; d < 10; ++d) dot += s_q[d * 44 + q] * s_k[d * 97 + jk];
      s_p[q * 91 + jk] = dot * SCALEF + s_kb[jk];
    }
  }
  __syncthreads();
  if (tid < 40) {
    float mx = -1e30f;
    for (int kx = 0; kx < nk; ++kx) mx = fmaxf(mx, s_p[tid * 91 + kx]);
    float sum = 0.f;
    for (int kx = 0; kx < nk; ++kx) {
      float ev = __expf(s_p[tid * 91 + kx] - mx);
      s_p[tid * 91 + kx] = ev;
      sum += ev;
    }
    s_den[tid] = 1.f / sum;
  }
  __syncthreads();
  // PV: all 64 lanes, 4 independent accumulators
  for (int pass = 0; pass < 7; ++pass) {
    int idx = pass * 64 + tid;
    if (idx < 400) {
      int q = idx / 10, d = idx % 10;
      float o0 = 0.f, o1 = 0.f, o2 = 0.f, o3 = 0.f;
      int kx = 0;
      int nk4 = nk & ~3;
      for (; kx < nk4; kx += 4) {
        o0 += s_p[q * 91 + kx]     * s_v[d * 97 + kx];
        o1 += s_p[q * 91 + kx + 1] * s_v[d * 97 + kx + 1];
        o2 += s_p[q * 91 + kx + 2] * s_v[d * 97 + kx + 2];
        o3 += s_p[q * 91 + kx + 3] * s_v[d * 97 + kx + 3];
      }
      for (; kx < nk; ++kx) o0 += s_p[q * 91 + kx] * s_v[d * 97 + kx];
      float o = (o0 + o1) + (o2 + o3);
      int qr = (q < RCC) ? i * RCC + q : RCL + i * SEGC + (q - RCC);
      attn[(b * KK + qr) * DD + h * 10 + d] = o * s_den[q];
    }
  }
}

// ---------------- S3: tail, hidden-split s in {0,1} --------------------------
// grid (ROWS/16, 2) = 320 blocks, block 256 (4 waves).
// Both halves compute oproj+res+LN_ff (cheap, redundant); each half does
// FFN1+FFN2 for hidden cols [1024s, 1024s+1024); s==0 adds b2+res into its
// partial. part[s] combined by k_comb2.
__global__ __launch_bounds__(256) void k_tail2(
    const float* __restrict__ attn, const unsigned short* __restrict__ wo,
    const float* __restrict__ bo, const unsigned short* __restrict__ w1,
    const float* __restrict__ b1, const unsigned short* __restrict__ w2,
    const float* __restrict__ b2, const float* __restrict__ fg,
    const float* __restrict__ fb, const float* __restrict__ x,
    float* __restrict__ part) {
  __shared__ float s_v[16 * 84];
  __shared__ unsigned short s_f[16 * 104];
  __shared__ unsigned short s_hw[4][16 * 140];
  __shared__ float s_part[4][16 * 84];
  __shared__ float s_mu[16], s_ri[16];
  int tid = threadIdx.x;
  int r0 = blockIdx.x * 16;
  int sH = blockIdx.y;
  int w = tid >> 6, lane = tid & 63;
  int m = lane & 15, q = lane >> 4;

  // ---- oproj ----
  bf16x8 af[3];
#pragma unroll
  for (int kk = 0; kk < 3; ++kk)
    af[kk] = fragf32(&attn[(r0 + m) * DD], kk * 32 + q * 8);
  f32x4 o0 = {};
#pragma unroll
  for (int kk = 0; kk < 3; ++kk) {
    bf16x8 b = fragbf(&wo[(w * 16 + m) * DD], kk * 32 + q * 8);
    o0 = __builtin_amdgcn_mfma_f32_16x16x32_bf16(af[kk], b, o0, 0, 0, 0);
  }
  f32x4 o1 = {};
  if (w == 0) {
#pragma unroll
    for (int kk = 0; kk < 3; ++kk) {
      bf16x8 b = fragbf(&wo[(64 + m) * DD], kk * 32 + q * 8);
      o1 = __builtin_amdgcn_mfma_f32_16x16x32_bf16(af[kk], b, o1, 0, 0, 0);
    }
  }
  {
    int c = w * 16 + m;
    float bv = bo[c];
#pragma unroll
    for (int r = 0; r < 4; ++r) {
      int lrow = q * 4 + r;
      s_v[lrow * 84 + c] = o0[r] + bv + x[(r0 + lrow) * DD + c];
    }
    if (w == 0) {
      int c4 = 64 + m;
      float bv4 = bo[c4];
#pragma unroll
      for (int r = 0; r < 4; ++r) {
        int lrow = q * 4 + r;
        s_v[lrow * 84 + c4] = o1[r] + bv4 + x[(r0 + lrow) * DD + c4];
      }
    }
  }
  __syncthreads();
  // ---- LN_ff stats ----
  if (tid < 64) {
    int row = tid & 15, prt = tid >> 4;
    float sm = 0.f, sq = 0.f;
    for (int j = 0; j < 20; ++j) {
      float v = s_v[row * 84 + prt * 20 + j];
      sm += v; sq += v * v;
    }
    sm += __shfl_xor(sm, 16); sq += __shfl_xor(sq, 16);
    sm += __shfl_xor(sm, 32); sq += __shfl_xor(sq, 32);
    if (prt == 0) {
      float mu = sm * (1.f / DD);
      s_mu[row] = mu;
      s_ri[row] = rsqrtf(sq * (1.f / DD) - mu * mu + EPSF);
    }
  }
  __syncthreads();
  {
    int row = tid >> 4, cg = tid & 15;
    float mu = s_mu[row], ri = s_ri[row];
#pragma unroll
    for (int j = 0; j < 5; ++j) {
      int c = cg * 5 + j;
      s_f[row * 104 + c] = f2bf((s_v[row * 84 + c] - mu) * ri * fg[c] + fb[c]);
    }
    if (cg == 15)
      for (int c = 80; c < 104; ++c) s_f[row * 104 + c] = 0;
  }
  __syncthreads();
  // ---- FFN1 + FFN2 over this block's hidden span ----
  bf16x8 ff[3];
#pragma unroll
  for (int kk = 0; kk < 3; ++kk)
    ff[kk] = *reinterpret_cast<const bf16x8*>(&s_f[m * 104 + kk * 32 + q * 8]);
  f32x4 acc2[5] = {};
  unsigned short* hw = &s_hw[w][0];
  int ws0 = sH * 1024 + w * 256;
  for (int sc = 0; sc < 2; ++sc) {
    int cc = ws0 + sc * 128;
#pragma unroll
    for (int t = 0; t < 8; ++t) {
      int col = cc + t * 16 + m;
      f32x4 a1 = {};
#pragma unroll
      for (int kk = 0; kk < 3; ++kk) {
        bf16x8 b = fragbf(&w1[col * DD], kk * 32 + q * 8);
        a1 = __builtin_amdgcn_mfma_f32_16x16x32_bf16(ff[kk], b, a1, 0, 0, 0);
      }
      float bb = b1[col];
#pragma unroll
      for (int r = 0; r < 4; ++r)
        hw[(q * 4 + r) * 140 + t * 16 + m] = f2bf(fmaxf(a1[r] + bb, 0.f));
    }
#pragma unroll
    for (int kk2 = 0; kk2 < 4; ++kk2) {
      bf16x8 ah = *reinterpret_cast<const bf16x8*>(&hw[m * 140 + kk2 * 32 + q * 8]);
#pragma unroll
      for (int t = 0; t < 5; ++t) {
        bf16x8 b = *reinterpret_cast<const bf16x8*>(
            &w2[(t * 16 + m) * FFND + cc + kk2 * 32 + q * 8]);
        acc2[t] = __builtin_amdgcn_mfma_f32_16x16x32_bf16(ah, b, acc2[t], 0, 0, 0);
      }
    }
  }
#pragma unroll
  for (int t = 0; t < 5; ++t)
#pragma unroll
    for (int r = 0; r < 4; ++r)
      s_part[w][(q * 4 + r) * 84 + t * 16 + m] = acc2[t][r];
  __syncthreads();
  // ---- reduce 4 waves, add b2+res on s==0, write part ----
  {
    int row = tid >> 4, cg = tid & 15;
#pragma unroll
    for (int j = 0; j < 5; ++j) {
      int c = cg * 5 + j;
      int o = row * 84 + c;
      float p = s_part[0][o] + s_part[1][o] + s_part[2][o] + s_part[3][o];
      if (sH == 0) p += b2[c] + s_v[o];
      part[sH * (ROWS * DD) + (r0 + row) * DD + c] = p;
    }
  }
}

// ---------------- S4: combine halves + LN_out -> x ----------------
// grid ROWS/4 = 640, block 256 (wave per row)
__global__ __launch_bounds__(256) void k_comb2(
    const float* __restrict__ part, float* __restrict__ x,
    const float* __restrict__ og, const float* __restrict__ ob) {
  int w = threadIdx.x >> 6, lane = threadIdx.x & 63;
  int row = blockIdx.x * 4 + w;
  const float* p0 = &part[row * DD];
  const float* p1 = &part[ROWS * DD + row * DD];
  float v1 = p0[lane] + p1[lane];
  float v2 = 0.f;
  if (lane < 16) v2 = p0[64 + lane] + p1[64 + lane];
  float sm = v1 + v2, sq = v1 * v1 + v2 * v2;
#pragma unroll
  for (int d2 = 1; d2 < 64; d2 <<= 1) {
    sm += __shfl_xor(sm, d2);
    sq += __shfl_xor(sq, d2);
  }
  float mu = sm * (1.f / DD);
  float ri = rsqrtf(sq * (1.f / DD) - mu * mu + EPSF);
  x[row * DD + lane] = (v1 - mu) * ri * og[lane] + ob[lane];
  if (lane < 16)
    x[row * DD + 64 + lane] = (v2 - mu) * ri * og[64 + lane] + ob[64 + lane];
}

// ---------------- P: final projection + lengths tail ----------------
__global__ __launch_bounds__(256) void k_projm(
    const float* __restrict__ x, const unsigned short* __restrict__ wp,
    const float* __restrict__ bp, const int* __restrict__ lengths,
    float* __restrict__ out) {
  __shared__ unsigned short s_a[64 * 104];
  __shared__ unsigned short s_w[64 * 104];
  int tid = threadIdx.x;
  int gr0 = blockIdx.x * 64;
  int c0 = blockIdx.y * 64;
  int b = gr0 / UU;
  int u0 = gr0 % UU;
  for (int k = 0; k < 5; ++k) {
    int idx = tid + k * 256;
    int row = idx / 20, c4 = idx % 20;
    float4 a = *reinterpret_cast<const float4*>(&x[(b * KK + RCL + u0 + row) * DD + c4 * 4]);
    *reinterpret_cast<ushort4*>(&s_a[row * 104 + c4 * 4]) = f4bf(a);
  }
  for (int k = 0; k < 3; ++k) {
    int idx = tid + k * 256;
    if (idx < 640) {
      int row = idx / 10, ch = idx % 10;
      *reinterpret_cast<uint4*>(&s_w[row * 104 + ch * 8]) =
          *reinterpret_cast<const uint4*>(&wp[(c0 + row) * DD + ch * 8]);
    }
  }
  if (tid < 128) {
    int row = tid >> 1, half = tid & 1;
    uint4 z = make_uint4(0, 0, 0, 0);
    *reinterpret_cast<uint4*>(&s_a[row * 104 + 80 + half * 8]) = z;
    *reinterpret_cast<uint4*>(&s_w[row * 104 + 80 + half * 8]) = z;
  }
  __syncthreads();
  int w = tid >> 6, lane = tid & 63;
  int m = lane & 15, q = lane >> 4;
  f32x4 acc[4] = {};
#pragma unroll
  for (int kk = 0; kk < 3; ++kk) {
    bf16x8 a = *reinterpret_cast<const bf16x8*>(&s_a[(w * 16 + m) * 104 + kk * 32 + q * 8]);
#pragma unroll
    for (int ct = 0; ct < 4; ++ct) {
      bf16x8 bfr = *reinterpret_cast<const bf16x8*>(&s_w[(ct * 16 + m) * 104 + kk * 32 + q * 8]);
      acc[ct] = __builtin_amdgcn_mfma_f32_16x16x32_bf16(a, bfr, acc[ct], 0, 0, 0);
    }
  }
#pragma unroll
  for (int ct = 0; ct < 4; ++ct) {
    int c = c0 + ct * 16 + m;
    float bv = bp[c];
#pragma unroll
    for (int r = 0; r < 4; ++r) {
      int grow = gr0 + w * 16 + q * 4 + r;
      out[grow * OUTD + c] = acc[ct][r] + bv;
    }
  }
  if (blockIdx.x == 0 && blockIdx.y == 0 && tid < BB)
    out[BB * UU * OUTD + tid] = (float)lengths[tid];
}

extern "C" void kernel_launch(void* const* d_in, const int* in_sizes, int n_in,
                              void* d_out, int out_size, void* d_ws, size_t ws_size,
                              hipStream_t stream) {
  const float* mel   = (const float*)d_in[0];
  const float* lng   = (const float*)d_in[1];
  const float* lnb   = (const float*)d_in[2];
  const float* Wq    = (const float*)d_in[3];
  const float* bq    = (const float*)d_in[4];
  const float* Wkv   = (const float*)d_in[5];
  const float* bkv   = (const float*)d_in[6];
  const float* Wo    = (const float*)d_in[7];
  const float* bo    = (const float*)d_in[8];
  const float* ffg   = (const float*)d_in[9];
  const float* ffb   = (const float*)d_in[10];
  const float* W1    = (const float*)d_in[11];
  const float* b1    = (const float*)d_in[12];
  const float* W2    = (const float*)d_in[13];
  const float* b2    = (const float*)d_in[14];
  const float* og    = (const float*)d_in[15];
  const float* ob    = (const float*)d_in[16];
  const float* Wp    = (const float*)d_in[17];
  const float* bp    = (const float*)d_in[18];
  const int*   lens  = (const int*)d_in[19];
  float* out = (float*)d_out;

  float* ws   = (float*)d_ws;
  float* x    = ws;                    // 204800 f
  float* qkv  = x + ROWS * DD;         // 614400 f
  float* attn = qkv + ROWS * 240;      // 204800 f
  float* part = attn + ROWS * DD;      // 2*204800 f
  unsigned short* w1bf  = (unsigned short*)(part + 2 * ROWS * DD);  // 1966080 sh
  unsigned short* w2bf  = w1bf + LL * FFND * DD;                    // 1966080 sh
  unsigned short* wqbf  = w2bf + LL * FFND * DD;                    // 76800 sh
  unsigned short* wkvbf = wqbf + LL * DD * DD;                      // 153600 sh
  unsigned short* wobf  = wkvbf + LL * 2 * DD * DD;                 // 76800 sh
  unsigned short* wpbf  = wobf + LL * DD * DD;                      // 61440 sh

  k_gather<<<800, 256, 0, stream>>>(mel, x);
  k_cvt<<<4200, 256, 0, stream>>>(W1, W2, Wq, Wkv, Wo, Wp,
                                  w1bf, w2bf, wqbf, wkvbf, wobf, wpbf);

  for (int l = 0; l < LL; ++l) {
    k_qkvt<<<dim3(ROWS / 16, 15), 64, 0, stream>>>(
        x, qkv, wqbf + l * DD * DD, bq + l * DD,
        wkvbf + l * 2 * DD * DD, bkv + l * 2 * DD,
        lng + l * DD, lnb + l * DD);
    k_attn<<<dim3(NSEG, HH, BB), 64, 0, stream>>>(qkv, attn, lens);
    k_tail2<<<dim3(ROWS / 16, 2), 256, 0, stream>>>(
        attn, wobf + l * DD * DD, bo + l * DD,
        w1bf + l * FFND * DD, b1 + l * FFND,
        w2bf + l * FFND * DD, b2 + l * DD,
        ffg + l * DD, ffb + l * DD, x, part);
    k_comb2<<<ROWS / 4, 256, 0, stream>>>(part, x, og + l * DD, ob + l * DD);
  }

  k_projm<<<dim3(BB * UU / 64, OUTD / 64), 256, 0, stream>>>(x, wpbf, bp, lens, out);
}